// Round 4
// baseline (64.780 us; speedup 1.0000x reference)
//
#include <hip/hip_runtime.h>
#include <math.h>

#define NN 256
#define EPSF 1e-7f
// 24-bit tag with three DISTINCT byte values: cannot be produced by any
// repeated-byte or repeated-dword poison fill of the 8B-aligned slots.
#define TAG24 0x9E3779ull

__device__ __forceinline__ float wave_reduce_sum(float v) {
    #pragma unroll
    for (int o = 32; o > 0; o >>= 1) v += __shfl_down(v, o, 64);
    return v;
}
__device__ __forceinline__ float wave_reduce_max(float v) {
    #pragma unroll
    for (int o = 32; o > 0; o >>= 1) v = fmaxf(v, __shfl_down(v, o, 64));
    return v;
}
__device__ __forceinline__ int swz(int j) { return j + (j >> 6); }  // break stride-32-element bank alias

// 2 blocks per batch (bx>>1 = batch, bx&1 = row-half). 256 threads:
// g = t>>3 picks a 4-row group, sub = t&7 picks a 32-wide j slice.
//
// Single-dispatch, fence-free handoff (round-2 protocol, kept):
//   producer: ONE relaxed agent-scope 64-bit atomic store {tag|flag|value};
//   consumer: block 511 spin-polls with relaxed agent-scope loads.
// Round-3 deltas:
//   (1) pass C consumes the j-slice from a 32xfloat2 REGISTER cache filled
//       during pass B (fully unrolled -> static indexing, no scratch) instead
//       of re-reading LDS — drops 32 ds_read_b64 + swizzle math per thread;
//   (2) consumer reads only 2 slots/thread: both halves carry the batch flag
//       bit, so sum(flagbits over 512 slots) == 2*nf exactly (integer in f32)
//       — third spin load removed; both loads issued before either check.
__global__ __launch_bounds__(256) void cox_fused(
    const float* __restrict__ pred,
    const float* __restrict__ target,
    const int* __restrict__ valid,
    unsigned long long* __restrict__ slots,  // [512] {tag24|flag8|value32}
    float* __restrict__ out)
{
    __shared__ float2 s_j[NN + 4];    // {tm_j, E_j = exp(pred_j)}, swizzled
    __shared__ float  s_pred[NN];
    __shared__ float  s_red[8];

    const int bx = blockIdx.x;
    const int b = bx >> 1, half = bx & 1;
    const int t = threadIdx.x;
    const int base = b * NN;

    const float p  = pred[base + t];
    const float tg = target[base + t];
    const bool  v  = valid[base + t] != 0;
    const float tm = v ? tg : -1.0f;
    const float E  = __expf(p);       // pred ~ N(0,1): no overflow, direct sum is f32-safe
    s_j[swz(t)] = make_float2(tm, E);
    s_pred[t] = p;

    const int wid = t >> 6, lane = t & 63;
    float wm = wave_reduce_max(tm);
    float wc = wave_reduce_sum(v ? 1.0f : 0.0f);
    if (lane == 0) { s_red[wid] = wm; s_red[4 + wid] = wc; }
    __syncthreads();                  // publishes s_j, s_pred, s_red
    const float bmax = fmaxf(fmaxf(s_red[0], s_red[1]), fmaxf(s_red[2], s_red[3]));
    const float vcount = s_red[4] + s_red[5] + s_red[6] + s_red[7];
    const float bmax_safe = fmaxf(bmax, 1.0f);

    const int g = t >> 3, sub = t & 7;
    const int i0 = half * 128 + g * 4;   // first of this thread's 4 rows
    const int j0 = sub * 32;             // this thread's j slice

    float ti[4], pi[4], Ei[4];
    #pragma unroll
    for (int r = 0; r < 4; r++) {
        float2 d = s_j[swz(i0 + r)];
        ti[r] = d.x; Ei[r] = d.y; pi[r] = s_pred[i0 + r];
    }

    // Pass B: den[r] = sum_{j: tm_j >= ti[r]} E_j; cache the slice in regs.
    float2 cj[32];                    // 64 VGPRs — fine at 2 blocks/CU
    float den[4] = {0.f, 0.f, 0.f, 0.f};
    #pragma unroll
    for (int k = 0; k < 32; k++) {
        float2 d = s_j[swz(j0 + k)];
        cj[k] = d;
        #pragma unroll
        for (int r = 0; r < 4; r++)
            den[r] += (d.x >= ti[r]) ? d.y : 0.0f;
    }
    #pragma unroll
    for (int r = 0; r < 4; r++) {
        den[r] += __shfl_xor(den[r], 1);
        den[r] += __shfl_xor(den[r], 2);
        den[r] += __shfl_xor(den[r], 4);
    }

    float invden[4], part1[4];
    #pragma unroll
    for (int r = 0; r < 4; r++) {
        invden[r] = 1.0f / den[r];
        part1[r]  = __logf(den[r]) - pi[r];   // -log_p_elim = log_den - pred_i
    }

    // Pass C: prod[r] = prod_{j in risk} max(1+eps - E_j/den, 2eps); register-only.
    const float c1 = 1.0f + EPSF, c2 = 2.0f * EPSF;
    float prod[4] = {1.f, 1.f, 1.f, 1.f};
    #pragma unroll
    for (int k = 0; k < 32; k++) {
        float2 d = cj[k];
        #pragma unroll
        for (int r = 0; r < 4; r++) {
            float term = fmaxf(fmaf(-d.y, invden[r], c1), c2);
            prod[r] *= (d.x >= ti[r]) ? term : 1.0f;
        }
    }
    #pragma unroll
    for (int r = 0; r < 4; r++) {
        prod[r] *= __shfl_xor(prod[r], 1);
        prod[r] *= __shfl_xor(prod[r], 2);
        prod[r] *= __shfl_xor(prod[r], 4);
    }

    float rsum = 0.0f;
    #pragma unroll
    for (int r = 0; r < 4; r++) {
        float tii  = fmaxf(fmaf(-Ei[r], invden[r], c1), c2);   // divide out j==i term
        float l2   = __logf(tii / prod[r]);                    // = -log(prod) + log(tii)
        float elim = ((ti[r] < bmax) && (ti[r] > 0.0f)) ? 1.0f : 0.0f;
        float w    = fminf(fmaxf((bmax - ti[r]) / bmax_safe, 0.0f), 1.0f);
        rsum += (part1[r] + l2) * elim * w;
    }
    rsum = (sub == 0) ? rsum : 0.0f;   // rows counted once across the 8 subs

    float wsum = wave_reduce_sum(rsum);
    __syncthreads();
    if (lane == 0) s_red[wid] = wsum;
    __syncthreads();
    if (t == 0) {
        float tot  = s_red[0] + s_red[1] + s_red[2] + s_red[3];
        float flag = (vcount >= 2.0f) ? 1.0f : 0.0f;
        unsigned long long pkt =
            (TAG24 << 40) |
            ((unsigned long long)(flag != 0.0f ? 1u : 0u) << 32) |
            (unsigned long long)__float_as_uint(tot * flag);
        // Single 8B atom carries readiness + payload: relaxed is sufficient.
        __hip_atomic_store(&slots[bx], pkt,
                           __ATOMIC_RELAXED, __HIP_MEMORY_SCOPE_AGENT);
    }

    if (bx != 511) return;

    // ---- consumer: block 511 (all 512 blocks co-resident at 2/CU) ----
    // Two slots per thread; issue both loads before either check so the
    // initial latencies overlap, then retry only the laggard.
    unsigned long long pa = __hip_atomic_load(&slots[t],      __ATOMIC_RELAXED, __HIP_MEMORY_SCOPE_AGENT);
    unsigned long long pb = __hip_atomic_load(&slots[NN + t], __ATOMIC_RELAXED, __HIP_MEMORY_SCOPE_AGENT);
    while ((pa >> 40) != TAG24)
        pa = __hip_atomic_load(&slots[t],      __ATOMIC_RELAXED, __HIP_MEMORY_SCOPE_AGENT);
    while ((pb >> 40) != TAG24)
        pb = __hip_atomic_load(&slots[NN + t], __ATOMIC_RELAXED, __HIP_MEMORY_SCOPE_AGENT);
    float fa = __uint_as_float((unsigned)(pa & 0xFFFFFFFFu));
    float fb = __uint_as_float((unsigned)(pb & 0xFFFFFFFFu));
    // Each batch's flag bit appears in BOTH its blocks' packets:
    // sum over all 512 slots of flagbit == 2*nf (small integers — exact).
    float fl = (float)(((unsigned)(pa >> 32) & 0xFFu) + ((unsigned)(pb >> 32) & 0xFFu));

    float rt = wave_reduce_sum(fa + fb);
    float rf = wave_reduce_sum(fl);
    __syncthreads();
    if (lane == 0) { s_red[wid] = rt; s_red[4 + wid] = rf; }
    __syncthreads();
    if (t == 0) {
        float tot = s_red[0] + s_red[1] + s_red[2] + s_red[3];
        float nf  = 0.5f * (s_red[4] + s_red[5] + s_red[6] + s_red[7]);
        out[0] = tot / fmaxf(nf, 1.0f);
    }
}

extern "C" void kernel_launch(void* const* d_in, const int* in_sizes, int n_in,
                              void* d_out, int out_size, void* d_ws, size_t ws_size,
                              hipStream_t stream) {
    const float* pred   = (const float*)d_in[0];
    const float* target = (const float*)d_in[1];
    const int*   valid  = (const int*)d_in[2];
    cox_fused<<<512, 256, 0, stream>>>(pred, target, valid,
                                       (unsigned long long*)d_ws, (float*)d_out);
}

// Round 5
// 62.878 us; speedup vs baseline: 1.0303x; 1.0303x over previous
//
#include <hip/hip_runtime.h>
#include <math.h>

#define NN 256
#define EPSF 1e-7f
// 24-bit tag with three DISTINCT byte values: cannot be produced by any
// repeated-byte or repeated-dword poison fill of the 8B-aligned slots.
#define TAG24 0x9E3779ull

__device__ __forceinline__ float wave_reduce_sum(float v) {
    #pragma unroll
    for (int o = 32; o > 0; o >>= 1) v += __shfl_down(v, o, 64);
    return v;
}
__device__ __forceinline__ float wave_reduce_max(float v) {
    #pragma unroll
    for (int o = 32; o > 0; o >>= 1) v = fmaxf(v, __shfl_down(v, o, 64));
    return v;
}
__device__ __forceinline__ int swz(int j) { return j + (j >> 6); }  // break stride-32-element bank alias

// 2 blocks per batch (bx>>1 = batch, bx&1 = row-half). 256 threads:
// g = t>>3 picks a 4-row group, sub = t&7 picks a 32-wide j slice.
//
// Single-dispatch, fence-free handoff (round-2 protocol, kept):
//   producer: ONE relaxed agent-scope 64-bit atomic store {tag|flag|value};
//   consumer: block 511 spin-polls with relaxed agent-scope loads.
// Round-4: REVERTED round-3's cj[32] register cache (it regressed +1.5us —
// pass C's LDS re-reads were fully latency-hidden at 8 waves/CU; the cache's
// +64 VGPR live ranges lengthened the schedule). Pass C re-reads LDS as in
// round 2. KEPT round-3's 2-slot consumer tail (flag bit travels in both
// halves' packets, so sum(flagbits)/2 == nf exactly; 2 overlapped spin loads
// instead of 3 serial ones).
__global__ __launch_bounds__(256) void cox_fused(
    const float* __restrict__ pred,
    const float* __restrict__ target,
    const int* __restrict__ valid,
    unsigned long long* __restrict__ slots,  // [512] {tag24|flag8|value32}
    float* __restrict__ out)
{
    __shared__ float2 s_j[NN + 4];    // {tm_j, E_j = exp(pred_j)}, swizzled
    __shared__ float  s_pred[NN];
    __shared__ float  s_red[8];

    const int bx = blockIdx.x;
    const int b = bx >> 1, half = bx & 1;
    const int t = threadIdx.x;
    const int base = b * NN;

    const float p  = pred[base + t];
    const float tg = target[base + t];
    const bool  v  = valid[base + t] != 0;
    const float tm = v ? tg : -1.0f;
    const float E  = __expf(p);       // pred ~ N(0,1): no overflow, direct sum is f32-safe
    s_j[swz(t)] = make_float2(tm, E);
    s_pred[t] = p;

    const int wid = t >> 6, lane = t & 63;
    float wm = wave_reduce_max(tm);
    float wc = wave_reduce_sum(v ? 1.0f : 0.0f);
    if (lane == 0) { s_red[wid] = wm; s_red[4 + wid] = wc; }
    __syncthreads();                  // publishes s_j, s_pred, s_red
    const float bmax = fmaxf(fmaxf(s_red[0], s_red[1]), fmaxf(s_red[2], s_red[3]));
    const float vcount = s_red[4] + s_red[5] + s_red[6] + s_red[7];
    const float bmax_safe = fmaxf(bmax, 1.0f);

    const int g = t >> 3, sub = t & 7;
    const int i0 = half * 128 + g * 4;   // first of this thread's 4 rows
    const int j0 = sub * 32;             // this thread's j slice

    float ti[4], pi[4], Ei[4];
    #pragma unroll
    for (int r = 0; r < 4; r++) {
        float2 d = s_j[swz(i0 + r)];
        ti[r] = d.x; Ei[r] = d.y; pi[r] = s_pred[i0 + r];
    }

    // Pass B: den[r] = sum_{j: tm_j >= ti[r]} E_j  (no transcendentals)
    float den[4] = {0.f, 0.f, 0.f, 0.f};
    #pragma unroll 4
    for (int k = 0; k < 32; k++) {
        float2 d = s_j[swz(j0 + k)];
        #pragma unroll
        for (int r = 0; r < 4; r++)
            den[r] += (d.x >= ti[r]) ? d.y : 0.0f;
    }
    #pragma unroll
    for (int r = 0; r < 4; r++) {
        den[r] += __shfl_xor(den[r], 1);
        den[r] += __shfl_xor(den[r], 2);
        den[r] += __shfl_xor(den[r], 4);
    }

    float invden[4], part1[4];
    #pragma unroll
    for (int r = 0; r < 4; r++) {
        invden[r] = 1.0f / den[r];
        part1[r]  = __logf(den[r]) - pi[r];   // -log_p_elim = log_den - pred_i
    }

    // Pass C: prod[r] = prod_{j in risk} max(1+eps - E_j/den, 2eps); one log per row.
    const float c1 = 1.0f + EPSF, c2 = 2.0f * EPSF;
    float prod[4] = {1.f, 1.f, 1.f, 1.f};
    #pragma unroll 4
    for (int k = 0; k < 32; k++) {
        float2 d = s_j[swz(j0 + k)];
        #pragma unroll
        for (int r = 0; r < 4; r++) {
            float term = fmaxf(fmaf(-d.y, invden[r], c1), c2);
            prod[r] *= (d.x >= ti[r]) ? term : 1.0f;
        }
    }
    #pragma unroll
    for (int r = 0; r < 4; r++) {
        prod[r] *= __shfl_xor(prod[r], 1);
        prod[r] *= __shfl_xor(prod[r], 2);
        prod[r] *= __shfl_xor(prod[r], 4);
    }

    float rsum = 0.0f;
    #pragma unroll
    for (int r = 0; r < 4; r++) {
        float tii  = fmaxf(fmaf(-Ei[r], invden[r], c1), c2);   // divide out j==i term
        float l2   = __logf(tii / prod[r]);                    // = -log(prod) + log(tii)
        float elim = ((ti[r] < bmax) && (ti[r] > 0.0f)) ? 1.0f : 0.0f;
        float w    = fminf(fmaxf((bmax - ti[r]) / bmax_safe, 0.0f), 1.0f);
        rsum += (part1[r] + l2) * elim * w;
    }
    rsum = (sub == 0) ? rsum : 0.0f;   // rows counted once across the 8 subs

    float wsum = wave_reduce_sum(rsum);
    __syncthreads();
    if (lane == 0) s_red[wid] = wsum;
    __syncthreads();
    if (t == 0) {
        float tot  = s_red[0] + s_red[1] + s_red[2] + s_red[3];
        float flag = (vcount >= 2.0f) ? 1.0f : 0.0f;
        unsigned long long pkt =
            (TAG24 << 40) |
            ((unsigned long long)(flag != 0.0f ? 1u : 0u) << 32) |
            (unsigned long long)__float_as_uint(tot * flag);
        // Single 8B atom carries readiness + payload: relaxed is sufficient.
        __hip_atomic_store(&slots[bx], pkt,
                           __ATOMIC_RELAXED, __HIP_MEMORY_SCOPE_AGENT);
    }

    if (bx != 511) return;

    // ---- consumer: block 511 (all 512 blocks co-resident at 2/CU) ----
    // Two slots per thread; issue both loads before either check so the
    // initial latencies overlap, then retry only the laggard.
    unsigned long long pa = __hip_atomic_load(&slots[t],      __ATOMIC_RELAXED, __HIP_MEMORY_SCOPE_AGENT);
    unsigned long long pb = __hip_atomic_load(&slots[NN + t], __ATOMIC_RELAXED, __HIP_MEMORY_SCOPE_AGENT);
    while ((pa >> 40) != TAG24)
        pa = __hip_atomic_load(&slots[t],      __ATOMIC_RELAXED, __HIP_MEMORY_SCOPE_AGENT);
    while ((pb >> 40) != TAG24)
        pb = __hip_atomic_load(&slots[NN + t], __ATOMIC_RELAXED, __HIP_MEMORY_SCOPE_AGENT);
    float fa = __uint_as_float((unsigned)(pa & 0xFFFFFFFFu));
    float fb = __uint_as_float((unsigned)(pb & 0xFFFFFFFFu));
    // Each batch's flag bit appears in BOTH its blocks' packets:
    // sum over all 512 slots of flagbit == 2*nf (small integers — exact).
    float fl = (float)(((unsigned)(pa >> 32) & 0xFFu) + ((unsigned)(pb >> 32) & 0xFFu));

    float rt = wave_reduce_sum(fa + fb);
    float rf = wave_reduce_sum(fl);
    __syncthreads();
    if (lane == 0) { s_red[wid] = rt; s_red[4 + wid] = rf; }
    __syncthreads();
    if (t == 0) {
        float tot = s_red[0] + s_red[1] + s_red[2] + s_red[3];
        float nf  = 0.5f * (s_red[4] + s_red[5] + s_red[6] + s_red[7]);
        out[0] = tot / fmaxf(nf, 1.0f);
    }
}

extern "C" void kernel_launch(void* const* d_in, const int* in_sizes, int n_in,
                              void* d_out, int out_size, void* d_ws, size_t ws_size,
                              hipStream_t stream) {
    const float* pred   = (const float*)d_in[0];
    const float* target = (const float*)d_in[1];
    const int*   valid  = (const int*)d_in[2];
    cox_fused<<<512, 256, 0, stream>>>(pred, target, valid,
                                       (unsigned long long*)d_ws, (float*)d_out);
}